// Round 1
// baseline (334.515 us; speedup 1.0000x reference)
//
#include <hip/hip_runtime.h>
#include <stdint.h>

typedef __bf16 bf16x8 __attribute__((ext_vector_type(8)));
typedef float f32x4 __attribute__((ext_vector_type(4)));

static constexpr float QK_SCALE = 0.044194173824159216f; // 1/sqrt(512)

__device__ __forceinline__ uint16_t f2bf(float f) {
    uint32_t x = __builtin_bit_cast(uint32_t, f);
    x += 0x7FFFu + ((x >> 16) & 1u);     // round-to-nearest-even; inputs finite
    return (uint16_t)(x >> 16);
}

// async 16B global->LDS copy (global_load_lds_dwordx4). LDS dest is
// wave-uniform base + lane*16; our lds ptr = base + tid*16 matches that.
__device__ __forceinline__ void cp16(const uint16_t* g, uint16_t* l) {
    __builtin_amdgcn_global_load_lds(
        (__attribute__((address_space(1))) void*)(uint16_t*)g,
        (__attribute__((address_space(3))) void*)l,
        16, 0, 0);
}

// ---------------------------------------------------------------------------
// NT GEMM: C[M,N] = A[M,K] * B[N,K]^T  (both operands K-contiguous, bf16)
// 128x128 tile, BK=32, 256 threads (4 waves in 2x2), mfma_f32_16x16x32_bf16.
// MODE 0: bf16 out, batched (blockIdx.z), scale, no bias
// MODE 2: f32 out + bias0 (final projection)
// MODE 3: QKV split epilogue: n<512 -> Q, <1024 -> K, else V transposed
// ---------------------------------------------------------------------------
template <int MODE>
__global__ __launch_bounds__(256) void gemm_nt(
    const uint16_t* __restrict__ A, const uint16_t* __restrict__ Bm,
    void* __restrict__ C0, void* __restrict__ C1, void* __restrict__ C2,
    const float* __restrict__ bias0, const float* __restrict__ bias1,
    const float* __restrict__ bias2,
    float scale, int K, int ldc, long bsA, long bsB, long bsC)
{
    __shared__ __align__(16) uint16_t As[128 * 32];
    __shared__ __align__(16) uint16_t Bs[128 * 32];

    const int t  = threadIdx.x;
    const int bn = blockIdx.x, bm = blockIdx.y, bz = blockIdx.z;
    const uint16_t* Ab = A  + (long)bz * bsA + (long)bm * 128 * K;
    const uint16_t* Bb = Bm + (long)bz * bsB + (long)bn * 128 * K;

    const int wave = t >> 6, lane = t & 63;
    const int wm = (wave >> 1) * 64, wn = (wave & 1) * 64;
    const int lm = lane & 15, lq = lane >> 4;

    f32x4 acc[4][4] = {};

    // staging: thread t loads 8 bf16 (16B): row = t>>2, col8 = (t&3)*8
    const long goff = (long)(t >> 2) * K + (t & 3) * 8;

    for (int k0 = 0; k0 < K; k0 += 32) {
        cp16(Ab + goff + k0,                As + t * 8);
        cp16(Ab + goff + (long)64 * K + k0, As + 2048 + t * 8);
        cp16(Bb + goff + k0,                Bs + t * 8);
        cp16(Bb + goff + (long)64 * K + k0, Bs + 2048 + t * 8);
        asm volatile("s_waitcnt vmcnt(0)" ::: "memory");
        __syncthreads();

        bf16x8 af[4], bfr[4];
#pragma unroll
        for (int i = 0; i < 4; ++i)
            af[i] = *(const bf16x8*)&As[(wm + i * 16 + lm) * 32 + lq * 8];
#pragma unroll
        for (int i = 0; i < 4; ++i)
            bfr[i] = *(const bf16x8*)&Bs[(wn + i * 16 + lm) * 32 + lq * 8];
#pragma unroll
        for (int i = 0; i < 4; ++i)
#pragma unroll
            for (int j = 0; j < 4; ++j)
                acc[i][j] = __builtin_amdgcn_mfma_f32_16x16x32_bf16(
                    af[i], bfr[j], acc[i][j], 0, 0, 0);
        __syncthreads();
    }

    // epilogue: C/D layout (m89/m91): m = (lane>>4)*4 + reg, n = lane&15
    const int mbase = bm * 128 + wm + lq * 4;
    const int nbase = bn * 128 + wn + lm;
#pragma unroll
    for (int i = 0; i < 4; ++i) {
#pragma unroll
        for (int j = 0; j < 4; ++j) {
            const int n = nbase + j * 16;
#pragma unroll
            for (int r = 0; r < 4; ++r) {
                const int m = mbase + i * 16 + r;
                const float v = acc[i][j][r] * scale;
                if (MODE == 0) {
                    ((uint16_t*)C0)[(long)bz * bsC + (long)m * ldc + n] = f2bf(v);
                } else if (MODE == 2) {
                    ((float*)C0)[(long)m * ldc + n] = v + bias0[n];
                } else { // MODE 3: QKV split (block-uniform branch: 128 | 512)
                    const int sec = n >> 9;
                    const int nn  = n & 511;
                    if (sec == 0) {
                        ((uint16_t*)C0)[(long)m * 512 + nn] = f2bf(v + bias0[nn]);
                    } else if (sec == 1) {
                        ((uint16_t*)C1)[(long)m * 512 + nn] = f2bf(v + bias1[nn]);
                    } else { // V stored transposed per batch: Vt[b][d][s]
                        const int bb = m >> 11, ss = m & 2047;
                        ((uint16_t*)C2)[((long)bb * 512 + nn) * 2048 + ss] =
                            f2bf(v + bias2[nn]);
                    }
                }
            }
        }
    }
}

// x + pos_table -> bf16, 8 elems/thread, exact grid (4096 blocks)
__global__ __launch_bounds__(256) void prep_x(const float* __restrict__ x,
                                              const float* __restrict__ pos,
                                              uint16_t* __restrict__ xb)
{
    const long i8 = ((long)blockIdx.x * 256 + threadIdx.x) * 8;
    const long p8 = i8 & ((1l << 20) - 1);   // S*D = 2^20
    const float4* xv = (const float4*)(x + i8);
    const float4* pv = (const float4*)(pos + p8);
    const float4 a0 = xv[0], a1 = xv[1];
    const float4 b0 = pv[0], b1 = pv[1];
    uint16_t o[8];
    o[0] = f2bf(a0.x + b0.x); o[1] = f2bf(a0.y + b0.y);
    o[2] = f2bf(a0.z + b0.z); o[3] = f2bf(a0.w + b0.w);
    o[4] = f2bf(a1.x + b1.x); o[5] = f2bf(a1.y + b1.y);
    o[6] = f2bf(a1.z + b1.z); o[7] = f2bf(a1.w + b1.w);
    *(uint4*)(xb + i8) = *(uint4*)o;
}

// Wq,Wk,Wv -> stacked wqkv[1536,512] bf16; Wd -> wd bf16. 512 blocks exact.
__global__ __launch_bounds__(256) void prep_w(
    const float* __restrict__ Wq, const float* __restrict__ Wk,
    const float* __restrict__ Wv, const float* __restrict__ Wd,
    uint16_t* __restrict__ wqkv, uint16_t* __restrict__ wd)
{
    const long f = ((long)blockIdx.x * 256 + threadIdx.x) * 8;
    const int  w = (int)(f >> 18);          // 262144 elems per weight
    const long off = f & 262143;
    const float* src = (w == 0) ? Wq : (w == 1) ? Wk : (w == 2) ? Wv : Wd;
    uint16_t* dst = (w < 3) ? (wqkv + (long)w * 262144 + off) : (wd + off);
    const float4* s4 = (const float4*)(src + off);
    const float4 a = s4[0], b = s4[1];
    uint16_t o[8];
    o[0] = f2bf(a.x); o[1] = f2bf(a.y); o[2] = f2bf(a.z); o[3] = f2bf(a.w);
    o[4] = f2bf(b.x); o[5] = f2bf(b.y); o[6] = f2bf(b.z); o[7] = f2bf(b.w);
    *(uint4*)dst = *(uint4*)o;
}

// in-place row softmax over bf16 P rows of length 2048; 1 block (256 thr)/row
__global__ __launch_bounds__(256) void softmax_rows(uint16_t* __restrict__ P)
{
    uint16_t* p = P + (long)blockIdx.x * 2048;
    const int t = threadIdx.x;
    const int lane = t & 63, wave = t >> 6;

    uint4 raw = *(const uint4*)(p + t * 8);
    uint32_t u[4] = {raw.x, raw.y, raw.z, raw.w};
    float x[8];
#pragma unroll
    for (int i = 0; i < 4; ++i) {
        x[2 * i]     = __builtin_bit_cast(float, u[i] << 16);
        x[2 * i + 1] = __builtin_bit_cast(float, u[i] & 0xFFFF0000u);
    }
    float mx = x[0];
#pragma unroll
    for (int i = 1; i < 8; ++i) mx = fmaxf(mx, x[i]);
#pragma unroll
    for (int off = 32; off; off >>= 1) mx = fmaxf(mx, __shfl_xor(mx, off));
    __shared__ float sm[4], ss[4];
    if (lane == 0) sm[wave] = mx;
    __syncthreads();
    mx = fmaxf(fmaxf(sm[0], sm[1]), fmaxf(sm[2], sm[3]));

    float sum = 0.f;
#pragma unroll
    for (int i = 0; i < 8; ++i) { x[i] = __expf(x[i] - mx); sum += x[i]; }
#pragma unroll
    for (int off = 32; off; off >>= 1) sum += __shfl_xor(sum, off);
    if (lane == 0) ss[wave] = sum;
    __syncthreads();
    const float inv = 1.f / (ss[0] + ss[1] + ss[2] + ss[3]);

#pragma unroll
    for (int i = 0; i < 4; ++i) {
        const uint32_t lo = f2bf(x[2 * i] * inv);
        const uint32_t hi = f2bf(x[2 * i + 1] * inv);
        u[i] = lo | (hi << 16);
    }
    *(uint4*)(p + t * 8) = make_uint4(u[0], u[1], u[2], u[3]);
}

extern "C" void kernel_launch(void* const* d_in, const int* in_sizes, int n_in,
                              void* d_out, int out_size, void* d_ws, size_t ws_size,
                              hipStream_t stream)
{
    const float* x   = (const float*)d_in[0];
    const float* pos = (const float*)d_in[1];
    const float* Wq  = (const float*)d_in[2];
    const float* bq  = (const float*)d_in[3];
    const float* Wk  = (const float*)d_in[4];
    const float* bk  = (const float*)d_in[5];
    const float* Wv  = (const float*)d_in[6];
    const float* bv  = (const float*)d_in[7];
    const float* Wd  = (const float*)d_in[8];
    const float* bd  = (const float*)d_in[9];
    float* out = (float*)d_out;

    // workspace layout (bytes), total 153,092,096
    char* ws = (char*)d_ws;
    uint16_t* xb   = (uint16_t*)(ws);                 // 16,777,216  [16384,512]
    uint16_t* wqkv = (uint16_t*)(ws + 16777216);      //  1,572,864  [1536,512]
    uint16_t* wd   = (uint16_t*)(ws + 18350080);      //    524,288  [512,512]
    uint16_t* Qb   = (uint16_t*)(ws + 18874368);      // 16,777,216  [16384,512]
    uint16_t* Kb   = (uint16_t*)(ws + 35651584);      // 16,777,216  [16384,512]
    uint16_t* Vt   = (uint16_t*)(ws + 52428800);      // 16,777,216  [8,512,2048]
    uint16_t* Pb   = (uint16_t*)(ws + 69206016);      // 67,108,864  [8,2048,2048]
    uint16_t* yb   = (uint16_t*)(ws + 136314880);     // 16,777,216  [16384,512]

    prep_x<<<4096, 256, 0, stream>>>(x, pos, xb);
    prep_w<<<512, 256, 0, stream>>>(Wq, Wk, Wv, Wd, wqkv, wd);

    // Q|K|Vt = xb @ wqkv^T (+bias):  M=16384, N=1536, K=512
    gemm_nt<3><<<dim3(12, 128, 1), 256, 0, stream>>>(
        xb, wqkv, Qb, Kb, Vt, bq, bk, bv, 1.0f, 512, 512, 0, 0, 0);

    // P[b] = (Q[b] @ K[b]^T) * scale:  8 x [2048,2048], K=512
    gemm_nt<0><<<dim3(16, 16, 8), 256, 0, stream>>>(
        Qb, Kb, Pb, nullptr, nullptr, nullptr, nullptr, nullptr,
        QK_SCALE, 512, 2048, (long)2048 * 512, (long)2048 * 512,
        (long)2048 * 2048);

    softmax_rows<<<16384, 256, 0, stream>>>(Pb);

    // y[b] = P[b] @ Vt[b]^T:  8 x [2048,512], K=2048
    gemm_nt<0><<<dim3(4, 16, 8), 256, 0, stream>>>(
        Pb, Vt, yb, nullptr, nullptr, nullptr, nullptr, nullptr,
        1.0f, 2048, 512, (long)2048 * 2048, (long)512 * 2048,
        (long)2048 * 512);

    // out = y @ wd^T + bd:  M=16384, N=512, K=512, fp32 out
    gemm_nt<2><<<dim3(4, 128, 1), 256, 0, stream>>>(
        yb, wd, out, nullptr, nullptr, bd, nullptr, nullptr,
        1.0f, 512, 512, 0, 0, 0);
}